// Round 6
// baseline (278.884 us; speedup 1.0000x reference)
//
#include <hip/hip_runtime.h>
#include <hip/hip_bf16.h>

#define TOK   8192      // B*T
#define NVAR  32
#define DDIM  64
#define HDIM  128
#define CDIM  64
#define ND    2048      // N*D
#define LN_EPS 1e-5f
#define TT 64

typedef float f32x4 __attribute__((ext_vector_type(4)));
typedef short s16x8 __attribute__((ext_vector_type(8)));
typedef unsigned short u16x8 __attribute__((ext_vector_type(8)));

__device__ __forceinline__ float bf2f(unsigned short u) {
    unsigned int x = ((unsigned int)u) << 16;
    return __uint_as_float(x);
}
__device__ __forceinline__ unsigned short f2bf(float f) {
    unsigned int x = __float_as_uint(f);
    unsigned int r = (x + 0x7fffu + ((x >> 16) & 1u)) >> 16;
    return (unsigned short)r;
}
__device__ __forceinline__ float elu_f(float x) {
    return x > 0.f ? x : (__expf(x) - 1.f);
}
__device__ __forceinline__ float sigm_f(float x) {
    return 1.f / (1.f + __expf(-x));
}
__device__ __forceinline__ s16x8 frag_ld(const unsigned short* p) {
    return __builtin_bit_cast(s16x8, *(const u16x8*)p);
}
__device__ __forceinline__ f32x4 mfma_bf16(s16x8 a, s16x8 b, f32x4 c) {
    return __builtin_amdgcn_mfma_f32_16x16x32_bf16(a, b, c, 0, 0, 0);
}

// ---------------- pack weight W[n][K][N] fp32 -> fragment-major bf16 ----------------
// out[n][ks][nf][lane][8]: element = W[n][ks*32 + (lane>>4)*8 + j][nf*16 + (lane&15)]
__global__ void k_pack(const float* __restrict__ W, unsigned short* __restrict__ out,
                       int K, int N) {
    int NF = N >> 4;
    int bx = blockIdx.x;              // ks*NF + nf
    int ks = bx / NF, nf = bx - ks * NF;
    int n = blockIdx.y;
    int lane = threadIdx.x;
    int col = nf * 16 + (lane & 15);
    int k0 = ks * 32 + (lane >> 4) * 8;
    const float* src = W + (size_t)n * K * N + (size_t)k0 * N + col;
    unsigned short* dst = out + (size_t)n * K * N + ((size_t)bx * 64 + lane) * 8;
    unsigned short v[8];
#pragma unroll
    for (int j = 0; j < 8; ++j) v[j] = f2bf(src[(size_t)j * N]);
    *(u16x8*)dst = *(const u16x8*)v;
}

// ---------------- ctx_proj = context @ f_Wc  [64,128] ----------------
__global__ void k_ctx(const float* __restrict__ ctx, const float* __restrict__ Wc,
                      float* __restrict__ ctxp) {
    int b = blockIdx.x, h = threadIdx.x;
    __shared__ float cs[CDIM];
    if (threadIdx.x < CDIM) cs[threadIdx.x] = ctx[b * CDIM + threadIdx.x];
    __syncthreads();
    float acc = 0.f;
#pragma unroll
    for (int c = 0; c < CDIM; ++c) acc += cs[c] * Wc[c * HDIM + h];
    ctxp[b * HDIM + h] = acc;
}

// ---------------- flatten GRN part 1 via MFMA: h1(bf16) + skip(f32) ----------------
// [8192,2048] @ [2048,160].  grid 256 x 32-token tiles, block 128 (2 waves, mf=w).
__global__ __launch_bounds__(128) void k_flat(const float* __restrict__ emb,
        const unsigned short* __restrict__ pfW1, const unsigned short* __restrict__ pfWsk,
        const float* __restrict__ fb1, const float* __restrict__ fbsk,
        const float* __restrict__ ctxp,
        unsigned short* __restrict__ h1b, float* __restrict__ skip) {
    const int tid = threadIdx.x;
    const int lane = tid & 63;
    const int w = tid >> 6;            // 0..1
    const int lr = lane & 15, lk = lane >> 4;
    const int tok0 = blockIdx.x * 32;
    const float* arow = emb + (size_t)(tok0 + w * 16 + lr) * ND + lk * 8;
    f32x4 acc[10] = {};
    for (int ks = 0; ks < 64; ++ks) {
        float4 a0 = *(const float4*)(arow + ks * 32);
        float4 a1 = *(const float4*)(arow + ks * 32 + 4);
        unsigned short av[8];
        av[0] = f2bf(a0.x); av[1] = f2bf(a0.y); av[2] = f2bf(a0.z); av[3] = f2bf(a0.w);
        av[4] = f2bf(a1.x); av[5] = f2bf(a1.y); av[6] = f2bf(a1.z); av[7] = f2bf(a1.w);
        s16x8 af = __builtin_bit_cast(s16x8, *(u16x8*)av);
#pragma unroll
        for (int nf = 0; nf < 8; ++nf) {
            s16x8 bf = frag_ld(pfW1 + ((size_t)(ks * 8 + nf) * 64 + lane) * 8);
            acc[nf] = mfma_bf16(af, bf, acc[nf]);
        }
#pragma unroll
        for (int nf = 0; nf < 2; ++nf) {
            s16x8 bf = frag_ld(pfWsk + ((size_t)(ks * 2 + nf) * 64 + lane) * 8);
            acc[8 + nf] = mfma_bf16(af, bf, acc[8 + nf]);
        }
    }
    const int b = tok0 >> 7;           // uniform per block (32 | 128)
#pragma unroll
    for (int nf = 0; nf < 8; ++nf) {
        int col = nf * 16 + lr;
        float add = fb1[col] + ctxp[b * HDIM + col];
#pragma unroll
        for (int r = 0; r < 4; ++r) {
            int tok = tok0 + w * 16 + lk * 4 + r;
            h1b[(size_t)tok * HDIM + col] = f2bf(elu_f(acc[nf][r] + add));
        }
    }
#pragma unroll
    for (int nf = 0; nf < 2; ++nf) {
        int col = nf * 16 + lr;
        float add = fbsk[col];
#pragma unroll
        for (int r = 0; r < 4; ++r) {
            int tok = tok0 + w * 16 + lk * 4 + r;
            skip[(size_t)tok * NVAR + col] = acc[8 + nf][r] + add;
        }
    }
}

// ---------------- selection via MFMA: h2, gates, glu+LN+softmax -> weights ----------------
// grid 256 x 32-token tiles, block 128 (2 waves).
__global__ __launch_bounds__(128) void k_sel(const unsigned short* __restrict__ h1b,
        const float* __restrict__ skip,
        const unsigned short* __restrict__ pfW2, const float* __restrict__ fb2,
        const unsigned short* __restrict__ pfWg, const float* __restrict__ fbg,
        const float* __restrict__ fg, const float* __restrict__ fb,
        float* __restrict__ wout) {
    __shared__ __align__(16) unsigned short pool[8704];
    unsigned short* H1 = pool;            // [32][136]
    unsigned short* H2 = pool + 4352;     // [32][136]
    const int tid = threadIdx.x;
    const int lane = tid & 63, w = tid >> 6, lr = lane & 15, lk = lane >> 4;
    const int tok0 = blockIdx.x * 32;

    // stage h1 tile (already bf16)
    {
        int row = tid >> 2, seg = (tid & 3) * 32;
#pragma unroll
        for (int q = 0; q < 4; ++q)
            *(u16x8*)(H1 + row * 136 + seg + q * 8) =
                *(const u16x8*)(h1b + (size_t)(tok0 + row) * HDIM + seg + q * 8);
    }
    __syncthreads();

    // phase A: H2 = H1@W2 + b2   (M=32,N=128,K=128)
    {
        f32x4 acc[8] = {};
#pragma unroll
        for (int ks = 0; ks < 4; ++ks) {
            s16x8 af = frag_ld(H1 + (w * 16 + lr) * 136 + ks * 32 + lk * 8);
#pragma unroll
            for (int nf = 0; nf < 8; ++nf) {
                s16x8 bf = frag_ld(pfW2 + ((size_t)(ks * 8 + nf) * 64 + lane) * 8);
                acc[nf] = mfma_bf16(af, bf, acc[nf]);
            }
        }
#pragma unroll
        for (int nf = 0; nf < 8; ++nf) {
            int col = nf * 16 + lr;
            float add = fb2[col];
#pragma unroll
            for (int r = 0; r < 4; ++r)
                H2[(w * 16 + lk * 4 + r) * 136 + col] = f2bf(acc[nf][r] + add);
        }
    }
    __syncthreads();   // all H1 reads done; G may overlay H1 after this point

    // phase B: G = H2@Wg + bg   (M=32,N=64,K=128), fp32 into LDS
    float* G = (float*)pool;              // [32][68], overlays H1 only
    {
        f32x4 acc[4] = {};
#pragma unroll
        for (int ks = 0; ks < 4; ++ks) {
            s16x8 af = frag_ld(H2 + (w * 16 + lr) * 136 + ks * 32 + lk * 8);
#pragma unroll
            for (int nf = 0; nf < 4; ++nf) {
                s16x8 bf = frag_ld(pfWg + ((size_t)(ks * 4 + nf) * 64 + lane) * 8);
                acc[nf] = mfma_bf16(af, bf, acc[nf]);
            }
        }
#pragma unroll
        for (int nf = 0; nf < 4; ++nf) {
            int col = nf * 16 + lr;
            float add = fbg[col];
#pragma unroll
            for (int r = 0; r < 4; ++r)
                G[(w * 16 + lk * 4 + r) * 68 + col] = acc[nf][r] + add;
        }
    }
    __syncthreads();

    // phase C: glu + skip, LN(32), softmax(32) -> weights
    {
        int grp = tid >> 5, t = tid & 31;
        float fgv = fg[t], fbv = fb[t];
#pragma unroll 2
        for (int j = 0; j < 8; ++j) {
            int tr = grp * 8 + j;
            float a = G[tr * 68 + t];
            float bb = G[tr * 68 + 32 + t];
            float val = a * sigm_f(bb) + skip[(size_t)(tok0 + tr) * NVAR + t];
            float s = val, q = val * val;
#pragma unroll
            for (int m = 16; m >= 1; m >>= 1) { s += __shfl_xor(s, m, 32); q += __shfl_xor(q, m, 32); }
            float mean = s * (1.f / 32.f);
            float var = q * (1.f / 32.f) - mean * mean;
            float logit = (val - mean) * rsqrtf(var + LN_EPS) * fgv + fbv;
            float mx = logit;
#pragma unroll
            for (int m = 16; m >= 1; m >>= 1) mx = fmaxf(mx, __shfl_xor(mx, m, 32));
            float e = __expf(logit - mx);
            float se = e;
#pragma unroll
            for (int m = 16; m >= 1; m >>= 1) se += __shfl_xor(se, m, 32);
            wout[(size_t)(tok0 + tr) * NVAR + t] = e / se;
        }
    }
}

// ---------------- per-variable GRNs via MFMA: VS & VG in registers ----------------
// grid (128 token-tiles, 8 n-groups of 4), block 256 (4 waves), TT=64.
// Wave w owns cols 32w..32w+31 in ALL phases; GLU pairs (c,c+128) in-lane.
// LDS 46592 B: EB[64][72]@0, VHB[64][136]@4608us, VH2B[64][136]@13312us,
//              LNp[64][4]f2@22016us, LNm[64]f2@23040us
__global__ __launch_bounds__(256, 3) void k_var(
        const float* __restrict__ emb,
        const unsigned short* __restrict__ pk1, const unsigned short* __restrict__ pksk,
        const unsigned short* __restrict__ pk2, const unsigned short* __restrict__ pkg,
        const float* __restrict__ vb1, const float* __restrict__ vbsk,
        const float* __restrict__ vb2, const float* __restrict__ vbg,
        const float* __restrict__ gam, const float* __restrict__ bet,
        const float* __restrict__ wsel, float* __restrict__ outp) {
    __shared__ __align__(16) unsigned short pool[23296];
    unsigned short* EB   = pool;                 // [64][72]
    unsigned short* VHB  = pool + 4608;          // [64][136]
    unsigned short* VH2B = pool + 13312;         // [64][136]
    float* LNp = (float*)(pool + 22016);         // [64][4][2]
    float* LNm = (float*)(pool + 23040);         // [64][2]

    const int tid = threadIdx.x;
    const int lane = tid & 63;
    const int w = tid >> 6;
    const int lr = lane & 15;
    const int lk = lane >> 4;
    const int tok0 = blockIdx.x * TT;
    const int gbase = blockIdx.y * 4;

    float accO[4][2][4] = {};

    for (int nn = 0; nn < 4; ++nn) {
        const int n = gbase + nn;

        // ---- stage E tile [64 tok][64] fp32 -> bf16 LDS (vectorized) ----
        {
            int row = tid >> 2, c0 = (tid & 3) * 16;
            const float* src = emb + ((size_t)(tok0 + row) * NVAR + n) * DDIM + c0;
            unsigned short* dst = EB + row * 72 + c0;
#pragma unroll
            for (int q = 0; q < 4; ++q) {
                float4 v = *(const float4*)(src + q * 4);
                ushort4 t;
                t.x = f2bf(v.x); t.y = f2bf(v.y); t.z = f2bf(v.z); t.w = f2bf(v.w);
                *(ushort4*)(dst + q * 4) = t;
            }
        }
        __syncthreads();

        // ---- phase 1: VH = elu(E@W1+b1) -> LDS;  VS = E@Wsk+bsk -> REGISTERS ----
        f32x4 c2[4][2];
#pragma unroll
        for (int mf = 0; mf < 4; ++mf)
#pragma unroll
            for (int nf = 0; nf < 2; ++nf) c2[mf][nf] = (f32x4){0.f, 0.f, 0.f, 0.f};
        {
            f32x4 c1[4][2] = {};
#pragma unroll
            for (int ks = 0; ks < 2; ++ks) {
                s16x8 af[4];
#pragma unroll
                for (int mf = 0; mf < 4; ++mf)
                    af[mf] = frag_ld(EB + (mf * 16 + lr) * 72 + ks * 32 + lk * 8);
                const unsigned short* p1 = pk1 + (size_t)n * 8192 + ((size_t)(ks * 8 + w * 2) * 64 + lane) * 8;
                const unsigned short* ps = pksk + (size_t)n * 8192 + ((size_t)(ks * 8 + w * 2) * 64 + lane) * 8;
                s16x8 b10 = frag_ld(p1), b11 = frag_ld(p1 + 512);
                s16x8 bs0 = frag_ld(ps), bs1 = frag_ld(ps + 512);
#pragma unroll
                for (int mf = 0; mf < 4; ++mf) {
                    c1[mf][0] = mfma_bf16(af[mf], b10, c1[mf][0]);
                    c1[mf][1] = mfma_bf16(af[mf], b11, c1[mf][1]);
                    c2[mf][0] = mfma_bf16(af[mf], bs0, c2[mf][0]);
                    c2[mf][1] = mfma_bf16(af[mf], bs1, c2[mf][1]);
                }
            }
#pragma unroll
            for (int nf = 0; nf < 2; ++nf) {
                int col = w * 32 + nf * 16 + lr;
                float bb1 = vb1[n * HDIM + col];
                float bbs = vbsk[n * HDIM + col];
#pragma unroll
                for (int mf = 0; mf < 4; ++mf) {
                    c2[mf][nf] = c2[mf][nf] + bbs;
#pragma unroll
                    for (int r = 0; r < 4; ++r)
                        VHB[(mf * 16 + lk * 4 + r) * 136 + col] = f2bf(elu_f(c1[mf][nf][r] + bb1));
                }
            }
        }
        __syncthreads();

        // ---- phase 2: VH2 = VH@W2+b2 -> LDS ----
        {
            f32x4 c3[4][2] = {};
#pragma unroll
            for (int ks = 0; ks < 4; ++ks) {
                s16x8 af[4];
#pragma unroll
                for (int mf = 0; mf < 4; ++mf)
                    af[mf] = frag_ld(VHB + (mf * 16 + lr) * 136 + ks * 32 + lk * 8);
                const unsigned short* p2 = pk2 + (size_t)n * 16384 + ((size_t)(ks * 8 + w * 2) * 64 + lane) * 8;
                s16x8 b0 = frag_ld(p2), b1 = frag_ld(p2 + 512);
#pragma unroll
                for (int mf = 0; mf < 4; ++mf) {
                    c3[mf][0] = mfma_bf16(af[mf], b0, c3[mf][0]);
                    c3[mf][1] = mfma_bf16(af[mf], b1, c3[mf][1]);
                }
            }
#pragma unroll
            for (int nf = 0; nf < 2; ++nf) {
                int col = w * 32 + nf * 16 + lr;
                float bb = vb2[n * HDIM + col];
#pragma unroll
                for (int mf = 0; mf < 4; ++mf)
#pragma unroll
                    for (int r = 0; r < 4; ++r)
                        VH2B[(mf * 16 + lk * 4 + r) * 136 + col] = f2bf(c3[mf][nf][r] + bb);
            }
        }
        __syncthreads();

        // ---- phase 3: VG in registers. Wave w: a-frags {2w,2w+1}, b-frags {2w+8,2w+9} ----
        float vv[4][2][4];
        float s_[4][4], q_[4][4];
        {
            f32x4 c4[4][4] = {};
#pragma unroll
            for (int ks = 0; ks < 4; ++ks) {
                s16x8 af[4];
#pragma unroll
                for (int mf = 0; mf < 4; ++mf)
                    af[mf] = frag_ld(VH2B + (mf * 16 + lr) * 136 + ks * 32 + lk * 8);
                const unsigned short* pg = pkg + (size_t)n * 32768;
                s16x8 ba0 = frag_ld(pg + ((size_t)(ks * 16 + 2 * w + 0) * 64 + lane) * 8);
                s16x8 ba1 = frag_ld(pg + ((size_t)(ks * 16 + 2 * w + 1) * 64 + lane) * 8);
                s16x8 bb0 = frag_ld(pg + ((size_t)(ks * 16 + 2 * w + 8) * 64 + lane) * 8);
                s16x8 bb1 = frag_ld(pg + ((size_t)(ks * 16 + 2 * w + 9) * 64 + lane) * 8);
#pragma unroll
                for (int mf = 0; mf < 4; ++mf) {
                    c4[mf][0] = mfma_bf16(af[mf], ba0, c4[mf][0]);
                    c4[mf][1] = mfma_bf16(af[mf], ba1, c4[mf][1]);
                    c4[mf][2] = mfma_bf16(af[mf], bb0, c4[mf][2]);
                    c4[mf][3] = mfma_bf16(af[mf], bb1, c4[mf][3]);
                }
            }
            // GLU + skip (in regs) + per-row partial sums
            float bga0 = vbg[n * 256 + w * 32 + lr];
            float bga1 = vbg[n * 256 + w * 32 + 16 + lr];
            float bgb0 = vbg[n * 256 + 128 + w * 32 + lr];
            float bgb1 = vbg[n * 256 + 128 + w * 32 + 16 + lr];
#pragma unroll
            for (int mf = 0; mf < 4; ++mf)
#pragma unroll
                for (int r = 0; r < 4; ++r) {
                    float a0 = c4[mf][0][r] + bga0;
                    float b0 = c4[mf][2][r] + bgb0;
                    float x0 = a0 * sigm_f(b0) + c2[mf][0][r];
                    float a1 = c4[mf][1][r] + bga1;
                    float b1 = c4[mf][3][r] + bgb1;
                    float x1 = a1 * sigm_f(b1) + c2[mf][1][r];
                    vv[mf][0][r] = x0; vv[mf][1][r] = x1;
                    s_[mf][r] = x0 + x1;
                    q_[mf][r] = x0 * x0 + x1 * x1;
                }
            // in-wave butterfly over lr (16 lanes) -> wave-partial per row
#pragma unroll
            for (int mf = 0; mf < 4; ++mf)
#pragma unroll
                for (int r = 0; r < 4; ++r) {
#pragma unroll
                    for (int m = 1; m < 16; m <<= 1) {
                        s_[mf][r] += __shfl_xor(s_[mf][r], m);
                        q_[mf][r] += __shfl_xor(q_[mf][r], m);
                    }
                }
            if (lr == 0) {
#pragma unroll
                for (int mf = 0; mf < 4; ++mf)
#pragma unroll
                    for (int r = 0; r < 4; ++r) {
                        int row = mf * 16 + lk * 4 + r;
                        LNp[row * 8 + w * 2] = s_[mf][r];
                        LNp[row * 8 + w * 2 + 1] = q_[mf][r];
                    }
            }
        }
        __syncthreads();

        // ---- cross-wave LN finish: 4 threads per row ----
        {
            int row = tid >> 2, p = tid & 3;
            float ss = LNp[row * 8 + p * 2];
            float qq = LNp[row * 8 + p * 2 + 1];
            ss += __shfl_xor(ss, 1); qq += __shfl_xor(qq, 1);
            ss += __shfl_xor(ss, 2); qq += __shfl_xor(qq, 2);
            if (p == 0) {
                float mean = ss * (1.f / 128.f);
                float var = qq * (1.f / 128.f) - mean * mean;
                LNm[row * 2] = mean;
                LNm[row * 2 + 1] = rsqrtf(var + LN_EPS);
            }
        }
        __syncthreads();

        // ---- combine: normalize, gamma/beta, *weight, accumulate in regs ----
        {
            float ga0 = gam[n * HDIM + w * 32 + lr];
            float ga1 = gam[n * HDIM + w * 32 + 16 + lr];
            float be0 = bet[n * HDIM + w * 32 + lr];
            float be1 = bet[n * HDIM + w * 32 + 16 + lr];
#pragma unroll
            for (int mf = 0; mf < 4; ++mf)
#pragma unroll
                for (int r = 0; r < 4; ++r) {
                    int row = mf * 16 + lk * 4 + r;
                    float mean = LNm[row * 2], inv = LNm[row * 2 + 1];
                    float wgt = wsel[(size_t)(tok0 + row) * NVAR + n];
                    accO[mf][0][r] += wgt * ((vv[mf][0][r] - mean) * inv * ga0 + be0);
                    accO[mf][1][r] += wgt * ((vv[mf][1][r] - mean) * inv * ga1 + be1);
                }
        }
        // no extra barrier needed: next stage writes EB only; all hazards
        // are separated by the stage/ph1/ph2/LNp/LNm barriers above.
    }

    // ---- one atomic per element per n-group ----
    {
#pragma unroll
        for (int mf = 0; mf < 4; ++mf)
#pragma unroll
            for (int r = 0; r < 4; ++r) {
                int row = mf * 16 + lk * 4 + r;
                float* po = outp + (size_t)(tok0 + row) * HDIM + w * 32 + lr;
                atomicAdd(po, accO[mf][0][r]);
                atomicAdd(po + 16, accO[mf][1][r]);
            }
    }
}

extern "C" void kernel_launch(void* const* d_in, const int* in_sizes, int n_in,
                              void* d_out, int out_size, void* d_ws, size_t ws_size,
                              hipStream_t stream) {
    const float* emb  = (const float*)d_in[0];
    const float* ctx  = (const float*)d_in[1];
    const float* fWsk = (const float*)d_in[2];
    const float* fbsk = (const float*)d_in[3];
    const float* fW1  = (const float*)d_in[4];
    const float* fb1  = (const float*)d_in[5];
    const float* fWc  = (const float*)d_in[6];
    const float* fW2  = (const float*)d_in[7];
    const float* fb2  = (const float*)d_in[8];
    const float* fWg  = (const float*)d_in[9];
    const float* fbg  = (const float*)d_in[10];
    const float* fg   = (const float*)d_in[11];
    const float* fb   = (const float*)d_in[12];
    const float* vWsk = (const float*)d_in[13];
    const float* vbsk = (const float*)d_in[14];
    const float* vW1  = (const float*)d_in[15];
    const float* vb1  = (const float*)d_in[16];
    const float* vW2  = (const float*)d_in[17];
    const float* vb2  = (const float*)d_in[18];
    const float* vWg  = (const float*)d_in[19];
    const float* vbg  = (const float*)d_in[20];
    const float* vgam = (const float*)d_in[21];
    const float* vbet = (const float*)d_in[22];

    float* outp = (float*)d_out;                       // [8192][128]
    float* wout = outp + (size_t)TOK * HDIM;           // [8192][32]

    // ---- workspace layout ----
    float* ctxp = (float*)d_ws;                        // [64][128]
    float* skip = ctxp + 64 * HDIM;                    // [8192][32] f32
    unsigned short* h1b  = (unsigned short*)(skip + (size_t)TOK * NVAR);  // [8192][128] bf16
    unsigned short* pk1  = h1b + (size_t)TOK * HDIM;   // [32][64][128]
    unsigned short* pksk = pk1 + 262144;               // [32][64][128]
    unsigned short* pk2  = pksk + 262144;              // [32][128][128]
    unsigned short* pkg  = pk2 + 524288;               // [32][128][256]
    unsigned short* pfW1 = pkg + 1048576;              // [2048][128] frag-packed
    unsigned short* pfWsk= pfW1 + 262144;              // [2048][32]
    unsigned short* pfW2 = pfWsk + 65536;              // [128][128]
    unsigned short* pfWg = pfW2 + 16384;               // [128][64]

    hipMemsetAsync(d_out, 0, (size_t)TOK * HDIM * sizeof(float), stream);
    // per-variable weight packs
    k_pack<<<dim3(16, 32), 64, 0, stream>>>(vW1, pk1, DDIM, HDIM);
    k_pack<<<dim3(16, 32), 64, 0, stream>>>(vWsk, pksk, DDIM, HDIM);
    k_pack<<<dim3(32, 32), 64, 0, stream>>>(vW2, pk2, HDIM, HDIM);
    k_pack<<<dim3(64, 32), 64, 0, stream>>>(vWg, pkg, HDIM, 2 * HDIM);
    // flatten weight packs
    k_pack<<<dim3(512, 1), 64, 0, stream>>>(fW1, pfW1, ND, HDIM);
    k_pack<<<dim3(128, 1), 64, 0, stream>>>(fWsk, pfWsk, ND, NVAR);
    k_pack<<<dim3(32, 1), 64, 0, stream>>>(fW2, pfW2, HDIM, HDIM);
    k_pack<<<dim3(16, 1), 64, 0, stream>>>(fWg, pfWg, HDIM, 64);

    k_ctx<<<64, 128, 0, stream>>>(ctx, fWc, ctxp);
    k_flat<<<256, 128, 0, stream>>>(emb, pfW1, pfWsk, fb1, fbsk, ctxp, h1b, skip);
    k_sel<<<256, 128, 0, stream>>>(h1b, skip, pfW2, fb2, pfWg, fbg, fg, fb, wout);
    k_var<<<dim3(TOK / TT, 8), 256, 0, stream>>>(emb, pk1, pksk, pk2, pkg,
                                                 vb1, vbsk, vb2, vbg, vgam, vbet,
                                                 wout, outp);
}

// Round 7
// 278.338 us; speedup vs baseline: 1.0020x; 1.0020x over previous
//
#include <hip/hip_runtime.h>
#include <hip/hip_bf16.h>

#define TOK   8192      // B*T
#define NVAR  32
#define DDIM  64
#define HDIM  128
#define CDIM  64
#define ND    2048      // N*D
#define LN_EPS 1e-5f
#define TT 64

typedef float f32x4 __attribute__((ext_vector_type(4)));
typedef short s16x8 __attribute__((ext_vector_type(8)));
typedef unsigned short u16x8 __attribute__((ext_vector_type(8)));

__device__ __forceinline__ float bf2f(unsigned short u) {
    unsigned int x = ((unsigned int)u) << 16;
    return __uint_as_float(x);
}
__device__ __forceinline__ unsigned short f2bf(float f) {
    unsigned int x = __float_as_uint(f);
    unsigned int r = (x + 0x7fffu + ((x >> 16) & 1u)) >> 16;
    return (unsigned short)r;
}
__device__ __forceinline__ float elu_f(float x) {
    return x > 0.f ? x : (__expf(x) - 1.f);
}
__device__ __forceinline__ float sigm_f(float x) {
    return 1.f / (1.f + __expf(-x));
}
__device__ __forceinline__ s16x8 frag_ld(const unsigned short* p) {
    return __builtin_bit_cast(s16x8, *(const u16x8*)p);
}
__device__ __forceinline__ f32x4 mfma_bf16(s16x8 a, s16x8 b, f32x4 c) {
    return __builtin_amdgcn_mfma_f32_16x16x32_bf16(a, b, c, 0, 0, 0);
}

// ---------------- pack weight W[n][K][N] fp32 -> fragment-major bf16 ----------------
// out[n][ks][nf][lane][8]: element = W[n][ks*32 + (lane>>4)*8 + j][nf*16 + (lane&15)]
__global__ void k_pack(const float* __restrict__ W, unsigned short* __restrict__ out,
                       int K, int N) {
    int NF = N >> 4;
    int bx = blockIdx.x;              // ks*NF + nf
    int ks = bx / NF, nf = bx - ks * NF;
    int n = blockIdx.y;
    int lane = threadIdx.x;
    int col = nf * 16 + (lane & 15);
    int k0 = ks * 32 + (lane >> 4) * 8;
    const float* src = W + (size_t)n * K * N + (size_t)k0 * N + col;
    unsigned short* dst = out + (size_t)n * K * N + ((size_t)bx * 64 + lane) * 8;
    unsigned short v[8];
#pragma unroll
    for (int j = 0; j < 8; ++j) v[j] = f2bf(src[(size_t)j * N]);
    *(u16x8*)dst = *(const u16x8*)v;
}

// ---------------- ctx_proj = context @ f_Wc  [64,128] ----------------
__global__ void k_ctx(const float* __restrict__ ctx, const float* __restrict__ Wc,
                      float* __restrict__ ctxp) {
    int b = blockIdx.x, h = threadIdx.x;
    __shared__ float cs[CDIM];
    if (threadIdx.x < CDIM) cs[threadIdx.x] = ctx[b * CDIM + threadIdx.x];
    __syncthreads();
    float acc = 0.f;
#pragma unroll
    for (int c = 0; c < CDIM; ++c) acc += cs[c] * Wc[c * HDIM + h];
    ctxp[b * HDIM + h] = acc;
}

// ---------------- flatten GRN part 1 via MFMA: h1(bf16) + skip(f32) ----------------
// [8192,2048] @ [2048,160].  grid 256 x 32-token tiles, block 128 (2 waves, mf=w).
__global__ __launch_bounds__(128) void k_flat(const float* __restrict__ emb,
        const unsigned short* __restrict__ pfW1, const unsigned short* __restrict__ pfWsk,
        const float* __restrict__ fb1, const float* __restrict__ fbsk,
        const float* __restrict__ ctxp,
        unsigned short* __restrict__ h1b, float* __restrict__ skip) {
    const int tid = threadIdx.x;
    const int lane = tid & 63;
    const int w = tid >> 6;            // 0..1
    const int lr = lane & 15, lk = lane >> 4;
    const int tok0 = blockIdx.x * 32;
    const float* arow = emb + (size_t)(tok0 + w * 16 + lr) * ND + lk * 8;
    f32x4 acc[10] = {};
    for (int ks = 0; ks < 64; ++ks) {
        float4 a0 = *(const float4*)(arow + ks * 32);
        float4 a1 = *(const float4*)(arow + ks * 32 + 4);
        unsigned short av[8];
        av[0] = f2bf(a0.x); av[1] = f2bf(a0.y); av[2] = f2bf(a0.z); av[3] = f2bf(a0.w);
        av[4] = f2bf(a1.x); av[5] = f2bf(a1.y); av[6] = f2bf(a1.z); av[7] = f2bf(a1.w);
        s16x8 af = __builtin_bit_cast(s16x8, *(u16x8*)av);
#pragma unroll
        for (int nf = 0; nf < 8; ++nf) {
            s16x8 bf = frag_ld(pfW1 + ((size_t)(ks * 8 + nf) * 64 + lane) * 8);
            acc[nf] = mfma_bf16(af, bf, acc[nf]);
        }
#pragma unroll
        for (int nf = 0; nf < 2; ++nf) {
            s16x8 bf = frag_ld(pfWsk + ((size_t)(ks * 2 + nf) * 64 + lane) * 8);
            acc[8 + nf] = mfma_bf16(af, bf, acc[8 + nf]);
        }
    }
    const int b = tok0 >> 7;           // uniform per block (32 | 128)
#pragma unroll
    for (int nf = 0; nf < 8; ++nf) {
        int col = nf * 16 + lr;
        float add = fb1[col] + ctxp[b * HDIM + col];
#pragma unroll
        for (int r = 0; r < 4; ++r) {
            int tok = tok0 + w * 16 + lk * 4 + r;
            h1b[(size_t)tok * HDIM + col] = f2bf(elu_f(acc[nf][r] + add));
        }
    }
#pragma unroll
    for (int nf = 0; nf < 2; ++nf) {
        int col = nf * 16 + lr;
        float add = fbsk[col];
#pragma unroll
        for (int r = 0; r < 4; ++r) {
            int tok = tok0 + w * 16 + lk * 4 + r;
            skip[(size_t)tok * NVAR + col] = acc[8 + nf][r] + add;
        }
    }
}

// ---------------- selection via MFMA: h2, gates, glu+LN+softmax -> weights ----------------
// grid 256 x 32-token tiles, block 128 (2 waves).
__global__ __launch_bounds__(128) void k_sel(const unsigned short* __restrict__ h1b,
        const float* __restrict__ skip,
        const unsigned short* __restrict__ pfW2, const float* __restrict__ fb2,
        const unsigned short* __restrict__ pfWg, const float* __restrict__ fbg,
        const float* __restrict__ fg, const float* __restrict__ fb,
        float* __restrict__ wout) {
    __shared__ __align__(16) unsigned short pool[8704];
    unsigned short* H1 = pool;            // [32][136]
    unsigned short* H2 = pool + 4352;     // [32][136]
    const int tid = threadIdx.x;
    const int lane = tid & 63, w = tid >> 6, lr = lane & 15, lk = lane >> 4;
    const int tok0 = blockIdx.x * 32;

    // stage h1 tile (already bf16)
    {
        int row = tid >> 2, seg = (tid & 3) * 32;
#pragma unroll
        for (int q = 0; q < 4; ++q)
            *(u16x8*)(H1 + row * 136 + seg + q * 8) =
                *(const u16x8*)(h1b + (size_t)(tok0 + row) * HDIM + seg + q * 8);
    }
    __syncthreads();

    // phase A: H2 = H1@W2 + b2   (M=32,N=128,K=128)
    {
        f32x4 acc[8] = {};
#pragma unroll
        for (int ks = 0; ks < 4; ++ks) {
            s16x8 af = frag_ld(H1 + (w * 16 + lr) * 136 + ks * 32 + lk * 8);
#pragma unroll
            for (int nf = 0; nf < 8; ++nf) {
                s16x8 bf = frag_ld(pfW2 + ((size_t)(ks * 8 + nf) * 64 + lane) * 8);
                acc[nf] = mfma_bf16(af, bf, acc[nf]);
            }
        }
#pragma unroll
        for (int nf = 0; nf < 8; ++nf) {
            int col = nf * 16 + lr;
            float add = fb2[col];
#pragma unroll
            for (int r = 0; r < 4; ++r)
                H2[(w * 16 + lk * 4 + r) * 136 + col] = f2bf(acc[nf][r] + add);
        }
    }
    __syncthreads();   // all H1 reads done; G may overlay H1 after this point

    // phase B: G = H2@Wg + bg   (M=32,N=64,K=128), fp32 into LDS
    float* G = (float*)pool;              // [32][68], overlays H1 only
    {
        f32x4 acc[4] = {};
#pragma unroll
        for (int ks = 0; ks < 4; ++ks) {
            s16x8 af = frag_ld(H2 + (w * 16 + lr) * 136 + ks * 32 + lk * 8);
#pragma unroll
            for (int nf = 0; nf < 4; ++nf) {
                s16x8 bf = frag_ld(pfWg + ((size_t)(ks * 4 + nf) * 64 + lane) * 8);
                acc[nf] = mfma_bf16(af, bf, acc[nf]);
            }
        }
#pragma unroll
        for (int nf = 0; nf < 4; ++nf) {
            int col = nf * 16 + lr;
            float add = fbg[col];
#pragma unroll
            for (int r = 0; r < 4; ++r)
                G[(w * 16 + lk * 4 + r) * 68 + col] = acc[nf][r] + add;
        }
    }
    __syncthreads();

    // phase C: glu + skip, LN(32), softmax(32) -> weights
    {
        int grp = tid >> 5, t = tid & 31;
        float fgv = fg[t], fbv = fb[t];
#pragma unroll 2
        for (int j = 0; j < 8; ++j) {
            int tr = grp * 8 + j;
            float a = G[tr * 68 + t];
            float bb = G[tr * 68 + 32 + t];
            float val = a * sigm_f(bb) + skip[(size_t)(tok0 + tr) * NVAR + t];
            float s = val, q = val * val;
#pragma unroll
            for (int m = 16; m >= 1; m >>= 1) { s += __shfl_xor(s, m, 32); q += __shfl_xor(q, m, 32); }
            float mean = s * (1.f / 32.f);
            float var = q * (1.f / 32.f) - mean * mean;
            float logit = (val - mean) * rsqrtf(var + LN_EPS) * fgv + fbv;
            float mx = logit;
#pragma unroll
            for (int m = 16; m >= 1; m >>= 1) mx = fmaxf(mx, __shfl_xor(mx, m, 32));
            float e = __expf(logit - mx);
            float se = e;
#pragma unroll
            for (int m = 16; m >= 1; m >>= 1) se += __shfl_xor(se, m, 32);
            wout[(size_t)(tok0 + tr) * NVAR + t] = e / se;
        }
    }
}

// ---------------- per-variable GRNs via MFMA: VS & VG in registers ----------------
// 1-D grid 512: group = bid&3 (8 n each, XCD-pinned to {g,g+4}), tile = bid>>2.
// Wave w owns cols 32w..32w+31 in ALL phases; GLU pairs (c,c+128) in-lane.
// LDS 46592 B: EB[64][72]@0, VHB[64][136]@4608us, VH2B[64][136]@13312us,
//              LNp[64][4]f2@22016us, LNm[64]f2@23040us
__global__ __launch_bounds__(256, 3) void k_var(
        const float* __restrict__ emb,
        const unsigned short* __restrict__ pk1, const unsigned short* __restrict__ pksk,
        const unsigned short* __restrict__ pk2, const unsigned short* __restrict__ pkg,
        const float* __restrict__ vb1, const float* __restrict__ vbsk,
        const float* __restrict__ vb2, const float* __restrict__ vbg,
        const float* __restrict__ gam, const float* __restrict__ bet,
        const float* __restrict__ wsel, float* __restrict__ outp) {
    __shared__ __align__(16) unsigned short pool[23296];
    unsigned short* EB   = pool;                 // [64][72]
    unsigned short* VHB  = pool + 4608;          // [64][136]
    unsigned short* VH2B = pool + 13312;         // [64][136]
    float* LNp = (float*)(pool + 22016);         // [64][4][2]
    float* LNm = (float*)(pool + 23040);         // [64][2]

    const int tid = threadIdx.x;
    const int lane = tid & 63;
    const int w = tid >> 6;
    const int lr = lane & 15;
    const int lk = lane >> 4;
    const int bid = blockIdx.x;
    const int tok0 = (bid >> 2) * TT;            // 128 token tiles
    const int gbase = (bid & 3) * 8;             // 4 n-groups of 8, XCD-pinned

    float accO[4][2][4] = {};

    for (int nn = 0; nn < 8; ++nn) {
        const int n = gbase + nn;

        // ---- stage E tile [64 tok][64] fp32 -> bf16 LDS (vectorized) ----
        {
            int row = tid >> 2, c0 = (tid & 3) * 16;
            const float* src = emb + ((size_t)(tok0 + row) * NVAR + n) * DDIM + c0;
            unsigned short* dst = EB + row * 72 + c0;
#pragma unroll
            for (int q = 0; q < 4; ++q) {
                float4 v = *(const float4*)(src + q * 4);
                ushort4 t;
                t.x = f2bf(v.x); t.y = f2bf(v.y); t.z = f2bf(v.z); t.w = f2bf(v.w);
                *(ushort4*)(dst + q * 4) = t;
            }
        }
        __syncthreads();

        // ---- phase 1: VH = elu(E@W1+b1) -> LDS;  VS = E@Wsk+bsk -> REGISTERS ----
        f32x4 c2[4][2];
#pragma unroll
        for (int mf = 0; mf < 4; ++mf)
#pragma unroll
            for (int nf = 0; nf < 2; ++nf) c2[mf][nf] = (f32x4){0.f, 0.f, 0.f, 0.f};
        {
            f32x4 c1[4][2] = {};
#pragma unroll
            for (int ks = 0; ks < 2; ++ks) {
                s16x8 af[4];
#pragma unroll
                for (int mf = 0; mf < 4; ++mf)
                    af[mf] = frag_ld(EB + (mf * 16 + lr) * 72 + ks * 32 + lk * 8);
                const unsigned short* p1 = pk1 + (size_t)n * 8192 + ((size_t)(ks * 8 + w * 2) * 64 + lane) * 8;
                const unsigned short* ps = pksk + (size_t)n * 8192 + ((size_t)(ks * 8 + w * 2) * 64 + lane) * 8;
                s16x8 b10 = frag_ld(p1), b11 = frag_ld(p1 + 512);
                s16x8 bs0 = frag_ld(ps), bs1 = frag_ld(ps + 512);
#pragma unroll
                for (int mf = 0; mf < 4; ++mf) {
                    c1[mf][0] = mfma_bf16(af[mf], b10, c1[mf][0]);
                    c1[mf][1] = mfma_bf16(af[mf], b11, c1[mf][1]);
                    c2[mf][0] = mfma_bf16(af[mf], bs0, c2[mf][0]);
                    c2[mf][1] = mfma_bf16(af[mf], bs1, c2[mf][1]);
                }
            }
#pragma unroll
            for (int nf = 0; nf < 2; ++nf) {
                int col = w * 32 + nf * 16 + lr;
                float bb1 = vb1[n * HDIM + col];
                float bbs = vbsk[n * HDIM + col];
#pragma unroll
                for (int mf = 0; mf < 4; ++mf) {
                    c2[mf][nf] = c2[mf][nf] + bbs;
#pragma unroll
                    for (int r = 0; r < 4; ++r)
                        VHB[(mf * 16 + lk * 4 + r) * 136 + col] = f2bf(elu_f(c1[mf][nf][r] + bb1));
                }
            }
        }
        __syncthreads();

        // ---- phase 2: VH2 = VH@W2+b2 -> LDS ----
        {
            f32x4 c3[4][2] = {};
#pragma unroll
            for (int ks = 0; ks < 4; ++ks) {
                s16x8 af[4];
#pragma unroll
                for (int mf = 0; mf < 4; ++mf)
                    af[mf] = frag_ld(VHB + (mf * 16 + lr) * 136 + ks * 32 + lk * 8);
                const unsigned short* p2 = pk2 + (size_t)n * 16384 + ((size_t)(ks * 8 + w * 2) * 64 + lane) * 8;
                s16x8 b0 = frag_ld(p2), b1 = frag_ld(p2 + 512);
#pragma unroll
                for (int mf = 0; mf < 4; ++mf) {
                    c3[mf][0] = mfma_bf16(af[mf], b0, c3[mf][0]);
                    c3[mf][1] = mfma_bf16(af[mf], b1, c3[mf][1]);
                }
            }
#pragma unroll
            for (int nf = 0; nf < 2; ++nf) {
                int col = w * 32 + nf * 16 + lr;
                float bb = vb2[n * HDIM + col];
#pragma unroll
                for (int mf = 0; mf < 4; ++mf)
#pragma unroll
                    for (int r = 0; r < 4; ++r)
                        VH2B[(mf * 16 + lk * 4 + r) * 136 + col] = f2bf(c3[mf][nf][r] + bb);
            }
        }
        __syncthreads();

        // ---- phase 3: VG in registers. Wave w: a-frags {2w,2w+1}, b-frags {2w+8,2w+9} ----
        float vv[4][2][4];
        float s_[4][4], q_[4][4];
        {
            f32x4 c4[4][4] = {};
#pragma unroll
            for (int ks = 0; ks < 4; ++ks) {
                s16x8 af[4];
#pragma unroll
                for (int mf = 0; mf < 4; ++mf)
                    af[mf] = frag_ld(VH2B + (mf * 16 + lr) * 136 + ks * 32 + lk * 8);
                const unsigned short* pg = pkg + (size_t)n * 32768;
                s16x8 ba0 = frag_ld(pg + ((size_t)(ks * 16 + 2 * w + 0) * 64 + lane) * 8);
                s16x8 ba1 = frag_ld(pg + ((size_t)(ks * 16 + 2 * w + 1) * 64 + lane) * 8);
                s16x8 bb0 = frag_ld(pg + ((size_t)(ks * 16 + 2 * w + 8) * 64 + lane) * 8);
                s16x8 bb1 = frag_ld(pg + ((size_t)(ks * 16 + 2 * w + 9) * 64 + lane) * 8);
#pragma unroll
                for (int mf = 0; mf < 4; ++mf) {
                    c4[mf][0] = mfma_bf16(af[mf], ba0, c4[mf][0]);
                    c4[mf][1] = mfma_bf16(af[mf], ba1, c4[mf][1]);
                    c4[mf][2] = mfma_bf16(af[mf], bb0, c4[mf][2]);
                    c4[mf][3] = mfma_bf16(af[mf], bb1, c4[mf][3]);
                }
            }
            // GLU + skip (in regs) + per-row partial sums
            float bga0 = vbg[n * 256 + w * 32 + lr];
            float bga1 = vbg[n * 256 + w * 32 + 16 + lr];
            float bgb0 = vbg[n * 256 + 128 + w * 32 + lr];
            float bgb1 = vbg[n * 256 + 128 + w * 32 + 16 + lr];
#pragma unroll
            for (int mf = 0; mf < 4; ++mf)
#pragma unroll
                for (int r = 0; r < 4; ++r) {
                    float a0 = c4[mf][0][r] + bga0;
                    float b0 = c4[mf][2][r] + bgb0;
                    float x0 = a0 * sigm_f(b0) + c2[mf][0][r];
                    float a1 = c4[mf][1][r] + bga1;
                    float b1 = c4[mf][3][r] + bgb1;
                    float x1 = a1 * sigm_f(b1) + c2[mf][1][r];
                    vv[mf][0][r] = x0; vv[mf][1][r] = x1;
                    s_[mf][r] = x0 + x1;
                    q_[mf][r] = x0 * x0 + x1 * x1;
                }
            // in-wave butterfly over lr (16 lanes) -> wave-partial per row
#pragma unroll
            for (int mf = 0; mf < 4; ++mf)
#pragma unroll
                for (int r = 0; r < 4; ++r) {
#pragma unroll
                    for (int m = 1; m < 16; m <<= 1) {
                        s_[mf][r] += __shfl_xor(s_[mf][r], m);
                        q_[mf][r] += __shfl_xor(q_[mf][r], m);
                    }
                }
            if (lr == 0) {
#pragma unroll
                for (int mf = 0; mf < 4; ++mf)
#pragma unroll
                    for (int r = 0; r < 4; ++r) {
                        int row = mf * 16 + lk * 4 + r;
                        LNp[row * 8 + w * 2] = s_[mf][r];
                        LNp[row * 8 + w * 2 + 1] = q_[mf][r];
                    }
            }
        }
        __syncthreads();

        // ---- cross-wave LN finish: 4 threads per row ----
        {
            int row = tid >> 2, p = tid & 3;
            float ss = LNp[row * 8 + p * 2];
            float qq = LNp[row * 8 + p * 2 + 1];
            ss += __shfl_xor(ss, 1); qq += __shfl_xor(qq, 1);
            ss += __shfl_xor(ss, 2); qq += __shfl_xor(qq, 2);
            if (p == 0) {
                float mean = ss * (1.f / 128.f);
                float var = qq * (1.f / 128.f) - mean * mean;
                LNm[row * 2] = mean;
                LNm[row * 2 + 1] = rsqrtf(var + LN_EPS);
            }
        }
        __syncthreads();

        // ---- combine: normalize, gamma/beta, *weight, accumulate in regs ----
        {
            float ga0 = gam[n * HDIM + w * 32 + lr];
            float ga1 = gam[n * HDIM + w * 32 + 16 + lr];
            float be0 = bet[n * HDIM + w * 32 + lr];
            float be1 = bet[n * HDIM + w * 32 + 16 + lr];
#pragma unroll
            for (int mf = 0; mf < 4; ++mf)
#pragma unroll
                for (int r = 0; r < 4; ++r) {
                    int row = mf * 16 + lk * 4 + r;
                    float mean = LNm[row * 2], inv = LNm[row * 2 + 1];
                    float wgt = wsel[(size_t)(tok0 + row) * NVAR + n];
                    accO[mf][0][r] += wgt * ((vv[mf][0][r] - mean) * inv * ga0 + be0);
                    accO[mf][1][r] += wgt * ((vv[mf][1][r] - mean) * inv * ga1 + be1);
                }
        }
        // next stage writes EB; hazards separated by the barriers above.
    }

    // ---- one atomic per element per n-group ----
    {
#pragma unroll
        for (int mf = 0; mf < 4; ++mf)
#pragma unroll
            for (int r = 0; r < 4; ++r) {
                int row = mf * 16 + lk * 4 + r;
                float* po = outp + (size_t)(tok0 + row) * HDIM + w * 32 + lr;
                atomicAdd(po, accO[mf][0][r]);
                atomicAdd(po + 16, accO[mf][1][r]);
            }
    }
}

extern "C" void kernel_launch(void* const* d_in, const int* in_sizes, int n_in,
                              void* d_out, int out_size, void* d_ws, size_t ws_size,
                              hipStream_t stream) {
    const float* emb  = (const float*)d_in[0];
    const float* ctx  = (const float*)d_in[1];
    const float* fWsk = (const float*)d_in[2];
    const float* fbsk = (const float*)d_in[3];
    const float* fW1  = (const float*)d_in[4];
    const float* fb1  = (const float*)d_in[5];
    const float* fWc  = (const float*)d_in[6];
    const float* fW2  = (const float*)d_in[7];
    const float* fb2  = (const float*)d_in[8];
    const float* fWg  = (const float*)d_in[9];
    const float* fbg  = (const float*)d_in[10];
    const float* fg   = (const float*)d_in[11];
    const float* fb   = (const float*)d_in[12];
    const float* vWsk = (const float*)d_in[13];
    const float* vbsk = (const float*)d_in[14];
    const float* vW1  = (const float*)d_in[15];
    const float* vb1  = (const float*)d_in[16];
    const float* vW2  = (const float*)d_in[17];
    const float* vb2  = (const float*)d_in[18];
    const float* vWg  = (const float*)d_in[19];
    const float* vbg  = (const float*)d_in[20];
    const float* vgam = (const float*)d_in[21];
    const float* vbet = (const float*)d_in[22];

    float* outp = (float*)d_out;                       // [8192][128]
    float* wout = outp + (size_t)TOK * HDIM;           // [8192][32]

    // ---- workspace layout ----
    float* ctxp = (float*)d_ws;                        // [64][128]
    float* skip = ctxp + 64 * HDIM;                    // [8192][32] f32
    unsigned short* h1b  = (unsigned short*)(skip + (size_t)TOK * NVAR);  // [8192][128] bf16
    unsigned short* pk1  = h1b + (size_t)TOK * HDIM;   // [32][64][128]
    unsigned short* pksk = pk1 + 262144;               // [32][64][128]
    unsigned short* pk2  = pksk + 262144;              // [32][128][128]
    unsigned short* pkg  = pk2 + 524288;               // [32][128][256]
    unsigned short* pfW1 = pkg + 1048576;              // [2048][128] frag-packed
    unsigned short* pfWsk= pfW1 + 262144;              // [2048][32]
    unsigned short* pfW2 = pfWsk + 65536;              // [128][128]
    unsigned short* pfWg = pfW2 + 16384;               // [128][64]

    hipMemsetAsync(d_out, 0, (size_t)TOK * HDIM * sizeof(float), stream);
    // per-variable weight packs
    k_pack<<<dim3(16, 32), 64, 0, stream>>>(vW1, pk1, DDIM, HDIM);
    k_pack<<<dim3(16, 32), 64, 0, stream>>>(vWsk, pksk, DDIM, HDIM);
    k_pack<<<dim3(32, 32), 64, 0, stream>>>(vW2, pk2, HDIM, HDIM);
    k_pack<<<dim3(64, 32), 64, 0, stream>>>(vWg, pkg, HDIM, 2 * HDIM);
    // flatten weight packs
    k_pack<<<dim3(512, 1), 64, 0, stream>>>(fW1, pfW1, ND, HDIM);
    k_pack<<<dim3(128, 1), 64, 0, stream>>>(fWsk, pfWsk, ND, NVAR);
    k_pack<<<dim3(32, 1), 64, 0, stream>>>(fW2, pfW2, HDIM, HDIM);
    k_pack<<<dim3(16, 1), 64, 0, stream>>>(fWg, pfWg, HDIM, 64);

    k_ctx<<<64, 128, 0, stream>>>(ctx, fWc, ctxp);
    k_flat<<<256, 128, 0, stream>>>(emb, pfW1, pfWsk, fb1, fbsk, ctxp, h1b, skip);
    k_sel<<<256, 128, 0, stream>>>(h1b, skip, pfW2, fb2, pfWg, fbg, fg, fb, wout);
    k_var<<<512, 256, 0, stream>>>(emb, pk1, pksk, pk2, pkg,
                                   vb1, vbsk, vb2, vbg, vgam, vbet,
                                   wout, outp);
}

// Round 8
// 192.986 us; speedup vs baseline: 1.4451x; 1.4423x over previous
//
#include <hip/hip_runtime.h>
#include <hip/hip_bf16.h>

#define TOK   8192      // B*T
#define NVAR  32
#define DDIM  64
#define HDIM  128
#define CDIM  64
#define ND    2048      // N*D
#define LN_EPS 1e-5f
#define TT 64

typedef float f32x4 __attribute__((ext_vector_type(4)));
typedef short s16x8 __attribute__((ext_vector_type(8)));
typedef unsigned short u16x8 __attribute__((ext_vector_type(8)));

__device__ __forceinline__ float bf2f(unsigned short u) {
    unsigned int x = ((unsigned int)u) << 16;
    return __uint_as_float(x);
}
__device__ __forceinline__ unsigned short f2bf(float f) {
    unsigned int x = __float_as_uint(f);
    unsigned int r = (x + 0x7fffu + ((x >> 16) & 1u)) >> 16;
    return (unsigned short)r;
}
__device__ __forceinline__ float elu_f(float x) {
    return x > 0.f ? x : (__expf(x) - 1.f);
}
__device__ __forceinline__ float sigm_f(float x) {
    return 1.f / (1.f + __expf(-x));
}
__device__ __forceinline__ s16x8 frag_ld(const unsigned short* p) {
    return __builtin_bit_cast(s16x8, *(const u16x8*)p);
}
__device__ __forceinline__ f32x4 mfma_bf16(s16x8 a, s16x8 b, f32x4 c) {
    return __builtin_amdgcn_mfma_f32_16x16x32_bf16(a, b, c, 0, 0, 0);
}

// ---------------- pack weight W[n][K][N] fp32 -> fragment-major bf16 ----------------
// out[n][ks][nf][lane][8]: element = W[n][ks*32 + (lane>>4)*8 + j][nf*16 + (lane&15)]
__global__ void k_pack(const float* __restrict__ W, unsigned short* __restrict__ out,
                       int K, int N) {
    int NF = N >> 4;
    int bx = blockIdx.x;              // ks*NF + nf
    int ks = bx / NF, nf = bx - ks * NF;
    int n = blockIdx.y;
    int lane = threadIdx.x;
    int col = nf * 16 + (lane & 15);
    int k0 = ks * 32 + (lane >> 4) * 8;
    const float* src = W + (size_t)n * K * N + (size_t)k0 * N + col;
    unsigned short* dst = out + (size_t)n * K * N + ((size_t)bx * 64 + lane) * 8;
    unsigned short v[8];
#pragma unroll
    for (int j = 0; j < 8; ++j) v[j] = f2bf(src[(size_t)j * N]);
    *(u16x8*)dst = *(const u16x8*)v;
}

// ---------------- ctx_proj = context @ f_Wc  [64,128] ----------------
__global__ void k_ctx(const float* __restrict__ ctx, const float* __restrict__ Wc,
                      float* __restrict__ ctxp) {
    int b = blockIdx.x, h = threadIdx.x;
    __shared__ float cs[CDIM];
    if (threadIdx.x < CDIM) cs[threadIdx.x] = ctx[b * CDIM + threadIdx.x];
    __syncthreads();
    float acc = 0.f;
#pragma unroll
    for (int c = 0; c < CDIM; ++c) acc += cs[c] * Wc[c * HDIM + h];
    ctxp[b * HDIM + h] = acc;
}

// ---------------- flatten GRN part 1 via MFMA: h1(bf16) + skip(f32) ----------------
// [8192,2048] @ [2048,160].  grid 256 x 32-token tiles, block 128 (2 waves, mf=w).
__global__ __launch_bounds__(128) void k_flat(const float* __restrict__ emb,
        const unsigned short* __restrict__ pfW1, const unsigned short* __restrict__ pfWsk,
        const float* __restrict__ fb1, const float* __restrict__ fbsk,
        const float* __restrict__ ctxp,
        unsigned short* __restrict__ h1b, float* __restrict__ skip) {
    const int tid = threadIdx.x;
    const int lane = tid & 63;
    const int w = tid >> 6;            // 0..1
    const int lr = lane & 15, lk = lane >> 4;
    const int tok0 = blockIdx.x * 32;
    const float* arow = emb + (size_t)(tok0 + w * 16 + lr) * ND + lk * 8;
    f32x4 acc[10] = {};
    for (int ks = 0; ks < 64; ++ks) {
        float4 a0 = *(const float4*)(arow + ks * 32);
        float4 a1 = *(const float4*)(arow + ks * 32 + 4);
        unsigned short av[8];
        av[0] = f2bf(a0.x); av[1] = f2bf(a0.y); av[2] = f2bf(a0.z); av[3] = f2bf(a0.w);
        av[4] = f2bf(a1.x); av[5] = f2bf(a1.y); av[6] = f2bf(a1.z); av[7] = f2bf(a1.w);
        s16x8 af = __builtin_bit_cast(s16x8, *(u16x8*)av);
#pragma unroll
        for (int nf = 0; nf < 8; ++nf) {
            s16x8 bf = frag_ld(pfW1 + ((size_t)(ks * 8 + nf) * 64 + lane) * 8);
            acc[nf] = mfma_bf16(af, bf, acc[nf]);
        }
#pragma unroll
        for (int nf = 0; nf < 2; ++nf) {
            s16x8 bf = frag_ld(pfWsk + ((size_t)(ks * 2 + nf) * 64 + lane) * 8);
            acc[8 + nf] = mfma_bf16(af, bf, acc[8 + nf]);
        }
    }
    const int b = tok0 >> 7;           // uniform per block (32 | 128)
#pragma unroll
    for (int nf = 0; nf < 8; ++nf) {
        int col = nf * 16 + lr;
        float add = fb1[col] + ctxp[b * HDIM + col];
#pragma unroll
        for (int r = 0; r < 4; ++r) {
            int tok = tok0 + w * 16 + lk * 4 + r;
            h1b[(size_t)tok * HDIM + col] = f2bf(elu_f(acc[nf][r] + add));
        }
    }
#pragma unroll
    for (int nf = 0; nf < 2; ++nf) {
        int col = nf * 16 + lr;
        float add = fbsk[col];
#pragma unroll
        for (int r = 0; r < 4; ++r) {
            int tok = tok0 + w * 16 + lk * 4 + r;
            skip[(size_t)tok * NVAR + col] = acc[8 + nf][r] + add;
        }
    }
}

// ---------------- selection via MFMA: h2, gates, glu+LN+softmax -> weights ----------------
// grid 256 x 32-token tiles, block 128 (2 waves).
__global__ __launch_bounds__(128) void k_sel(const unsigned short* __restrict__ h1b,
        const float* __restrict__ skip,
        const unsigned short* __restrict__ pfW2, const float* __restrict__ fb2,
        const unsigned short* __restrict__ pfWg, const float* __restrict__ fbg,
        const float* __restrict__ fg, const float* __restrict__ fb,
        float* __restrict__ wout) {
    __shared__ __align__(16) unsigned short pool[8704];
    unsigned short* H1 = pool;            // [32][136]
    unsigned short* H2 = pool + 4352;     // [32][136]
    const int tid = threadIdx.x;
    const int lane = tid & 63, w = tid >> 6, lr = lane & 15, lk = lane >> 4;
    const int tok0 = blockIdx.x * 32;

    // stage h1 tile (already bf16)
    {
        int row = tid >> 2, seg = (tid & 3) * 32;
#pragma unroll
        for (int q = 0; q < 4; ++q)
            *(u16x8*)(H1 + row * 136 + seg + q * 8) =
                *(const u16x8*)(h1b + (size_t)(tok0 + row) * HDIM + seg + q * 8);
    }
    __syncthreads();

    // phase A: H2 = H1@W2 + b2   (M=32,N=128,K=128)
    {
        f32x4 acc[8] = {};
#pragma unroll
        for (int ks = 0; ks < 4; ++ks) {
            s16x8 af = frag_ld(H1 + (w * 16 + lr) * 136 + ks * 32 + lk * 8);
#pragma unroll
            for (int nf = 0; nf < 8; ++nf) {
                s16x8 bf = frag_ld(pfW2 + ((size_t)(ks * 8 + nf) * 64 + lane) * 8);
                acc[nf] = mfma_bf16(af, bf, acc[nf]);
            }
        }
#pragma unroll
        for (int nf = 0; nf < 8; ++nf) {
            int col = nf * 16 + lr;
            float add = fb2[col];
#pragma unroll
            for (int r = 0; r < 4; ++r)
                H2[(w * 16 + lk * 4 + r) * 136 + col] = f2bf(acc[nf][r] + add);
        }
    }
    __syncthreads();   // all H1 reads done; G may overlay H1 after this point

    // phase B: G = H2@Wg + bg   (M=32,N=64,K=128), fp32 into LDS
    float* G = (float*)pool;              // [32][68], overlays H1 only
    {
        f32x4 acc[4] = {};
#pragma unroll
        for (int ks = 0; ks < 4; ++ks) {
            s16x8 af = frag_ld(H2 + (w * 16 + lr) * 136 + ks * 32 + lk * 8);
#pragma unroll
            for (int nf = 0; nf < 4; ++nf) {
                s16x8 bf = frag_ld(pfWg + ((size_t)(ks * 4 + nf) * 64 + lane) * 8);
                acc[nf] = mfma_bf16(af, bf, acc[nf]);
            }
        }
#pragma unroll
        for (int nf = 0; nf < 4; ++nf) {
            int col = nf * 16 + lr;
            float add = fbg[col];
#pragma unroll
            for (int r = 0; r < 4; ++r)
                G[(w * 16 + lk * 4 + r) * 68 + col] = acc[nf][r] + add;
        }
    }
    __syncthreads();

    // phase C: glu + skip, LN(32), softmax(32) -> weights
    {
        int grp = tid >> 5, t = tid & 31;
        float fgv = fg[t], fbv = fb[t];
#pragma unroll 2
        for (int j = 0; j < 8; ++j) {
            int tr = grp * 8 + j;
            float a = G[tr * 68 + t];
            float bb = G[tr * 68 + 32 + t];
            float val = a * sigm_f(bb) + skip[(size_t)(tok0 + tr) * NVAR + t];
            float s = val, q = val * val;
#pragma unroll
            for (int m = 16; m >= 1; m >>= 1) { s += __shfl_xor(s, m, 32); q += __shfl_xor(q, m, 32); }
            float mean = s * (1.f / 32.f);
            float var = q * (1.f / 32.f) - mean * mean;
            float logit = (val - mean) * rsqrtf(var + LN_EPS) * fgv + fbv;
            float mx = logit;
#pragma unroll
            for (int m = 16; m >= 1; m >>= 1) mx = fmaxf(mx, __shfl_xor(mx, m, 32));
            float e = __expf(logit - mx);
            float se = e;
#pragma unroll
            for (int m = 16; m >= 1; m >>= 1) se += __shfl_xor(se, m, 32);
            wout[(size_t)(tok0 + tr) * NVAR + t] = e / se;
        }
    }
}

// ---------------- per-variable GRNs via MFMA: VS & VG in registers ----------------
// grid dim3(128 tiles, 4 groups of 8 n) — r5's proven locality ordering.
// Wave w owns cols 32w..32w+31 in ALL phases; GLU pairs (c,c+128) in-lane.
// __launch_bounds__(256,2): 256-VGPR cap, NO SPILL (r6/r7's (256,3) forced
// an 84-VGPR cap -> ~200MB scratch traffic; that was the regression).
// LDS 46592 B: EB[64][72]@0, VHB[64][136]@4608us, VH2B[64][136]@13312us,
//              LNp[64][4]f2@22016us, LNm[64]f2@23040us
__global__ __launch_bounds__(256, 2) void k_var(
        const float* __restrict__ emb,
        const unsigned short* __restrict__ pk1, const unsigned short* __restrict__ pksk,
        const unsigned short* __restrict__ pk2, const unsigned short* __restrict__ pkg,
        const float* __restrict__ vb1, const float* __restrict__ vbsk,
        const float* __restrict__ vb2, const float* __restrict__ vbg,
        const float* __restrict__ gam, const float* __restrict__ bet,
        const float* __restrict__ wsel, float* __restrict__ outp) {
    __shared__ __align__(16) unsigned short pool[23296];
    unsigned short* EB   = pool;                 // [64][72]
    unsigned short* VHB  = pool + 4608;          // [64][136]
    unsigned short* VH2B = pool + 13312;         // [64][136]
    float* LNp = (float*)(pool + 22016);         // [64][4][2]
    float* LNm = (float*)(pool + 23040);         // [64][2]

    const int tid = threadIdx.x;
    const int lane = tid & 63;
    const int w = tid >> 6;
    const int lr = lane & 15;
    const int lk = lane >> 4;
    const int tok0 = blockIdx.x * TT;
    const int gbase = blockIdx.y * 8;

    float accO[4][2][4] = {};

    for (int nn = 0; nn < 8; ++nn) {
        const int n = gbase + nn;

        // ---- stage E tile [64 tok][64] fp32 -> bf16 LDS (vectorized) ----
        {
            int row = tid >> 2, c0 = (tid & 3) * 16;
            const float* src = emb + ((size_t)(tok0 + row) * NVAR + n) * DDIM + c0;
            unsigned short* dst = EB + row * 72 + c0;
#pragma unroll
            for (int q = 0; q < 4; ++q) {
                float4 v = *(const float4*)(src + q * 4);
                ushort4 t;
                t.x = f2bf(v.x); t.y = f2bf(v.y); t.z = f2bf(v.z); t.w = f2bf(v.w);
                *(ushort4*)(dst + q * 4) = t;
            }
        }
        __syncthreads();

        // ---- phase 1: VH = elu(E@W1+b1) -> LDS;  VS = E@Wsk+bsk -> REGISTERS ----
        f32x4 c2[4][2];
#pragma unroll
        for (int mf = 0; mf < 4; ++mf)
#pragma unroll
            for (int nf = 0; nf < 2; ++nf) c2[mf][nf] = (f32x4){0.f, 0.f, 0.f, 0.f};
        {
            f32x4 c1[4][2] = {};
#pragma unroll
            for (int ks = 0; ks < 2; ++ks) {
                s16x8 af[4];
#pragma unroll
                for (int mf = 0; mf < 4; ++mf)
                    af[mf] = frag_ld(EB + (mf * 16 + lr) * 72 + ks * 32 + lk * 8);
                const unsigned short* p1 = pk1 + (size_t)n * 8192 + ((size_t)(ks * 8 + w * 2) * 64 + lane) * 8;
                const unsigned short* ps = pksk + (size_t)n * 8192 + ((size_t)(ks * 8 + w * 2) * 64 + lane) * 8;
                s16x8 b10 = frag_ld(p1), b11 = frag_ld(p1 + 512);
                s16x8 bs0 = frag_ld(ps), bs1 = frag_ld(ps + 512);
#pragma unroll
                for (int mf = 0; mf < 4; ++mf) {
                    c1[mf][0] = mfma_bf16(af[mf], b10, c1[mf][0]);
                    c1[mf][1] = mfma_bf16(af[mf], b11, c1[mf][1]);
                    c2[mf][0] = mfma_bf16(af[mf], bs0, c2[mf][0]);
                    c2[mf][1] = mfma_bf16(af[mf], bs1, c2[mf][1]);
                }
            }
#pragma unroll
            for (int nf = 0; nf < 2; ++nf) {
                int col = w * 32 + nf * 16 + lr;
                float bb1 = vb1[n * HDIM + col];
                float bbs = vbsk[n * HDIM + col];
#pragma unroll
                for (int mf = 0; mf < 4; ++mf) {
                    c2[mf][nf] = c2[mf][nf] + bbs;
#pragma unroll
                    for (int r = 0; r < 4; ++r)
                        VHB[(mf * 16 + lk * 4 + r) * 136 + col] = f2bf(elu_f(c1[mf][nf][r] + bb1));
                }
            }
        }
        __syncthreads();

        // ---- phase 2: VH2 = VH@W2+b2 -> LDS ----
        {
            f32x4 c3[4][2] = {};
#pragma unroll
            for (int ks = 0; ks < 4; ++ks) {
                s16x8 af[4];
#pragma unroll
                for (int mf = 0; mf < 4; ++mf)
                    af[mf] = frag_ld(VHB + (mf * 16 + lr) * 136 + ks * 32 + lk * 8);
                const unsigned short* p2 = pk2 + (size_t)n * 16384 + ((size_t)(ks * 8 + w * 2) * 64 + lane) * 8;
                s16x8 b0 = frag_ld(p2), b1 = frag_ld(p2 + 512);
#pragma unroll
                for (int mf = 0; mf < 4; ++mf) {
                    c3[mf][0] = mfma_bf16(af[mf], b0, c3[mf][0]);
                    c3[mf][1] = mfma_bf16(af[mf], b1, c3[mf][1]);
                }
            }
#pragma unroll
            for (int nf = 0; nf < 2; ++nf) {
                int col = w * 32 + nf * 16 + lr;
                float bb = vb2[n * HDIM + col];
#pragma unroll
                for (int mf = 0; mf < 4; ++mf)
#pragma unroll
                    for (int r = 0; r < 4; ++r)
                        VH2B[(mf * 16 + lk * 4 + r) * 136 + col] = f2bf(c3[mf][nf][r] + bb);
            }
        }
        __syncthreads();

        // ---- phase 3: VG in registers. Wave w: a-frags {2w,2w+1}, b-frags {2w+8,2w+9} ----
        float vv[4][2][4];
        float s_[4][4], q_[4][4];
        {
            f32x4 c4[4][4] = {};
#pragma unroll
            for (int ks = 0; ks < 4; ++ks) {
                s16x8 af[4];
#pragma unroll
                for (int mf = 0; mf < 4; ++mf)
                    af[mf] = frag_ld(VH2B + (mf * 16 + lr) * 136 + ks * 32 + lk * 8);
                const unsigned short* pg = pkg + (size_t)n * 32768;
                s16x8 ba0 = frag_ld(pg + ((size_t)(ks * 16 + 2 * w + 0) * 64 + lane) * 8);
                s16x8 ba1 = frag_ld(pg + ((size_t)(ks * 16 + 2 * w + 1) * 64 + lane) * 8);
                s16x8 bb0 = frag_ld(pg + ((size_t)(ks * 16 + 2 * w + 8) * 64 + lane) * 8);
                s16x8 bb1 = frag_ld(pg + ((size_t)(ks * 16 + 2 * w + 9) * 64 + lane) * 8);
#pragma unroll
                for (int mf = 0; mf < 4; ++mf) {
                    c4[mf][0] = mfma_bf16(af[mf], ba0, c4[mf][0]);
                    c4[mf][1] = mfma_bf16(af[mf], ba1, c4[mf][1]);
                    c4[mf][2] = mfma_bf16(af[mf], bb0, c4[mf][2]);
                    c4[mf][3] = mfma_bf16(af[mf], bb1, c4[mf][3]);
                }
            }
            // GLU + skip (in regs) + per-row partial sums
            float bga0 = vbg[n * 256 + w * 32 + lr];
            float bga1 = vbg[n * 256 + w * 32 + 16 + lr];
            float bgb0 = vbg[n * 256 + 128 + w * 32 + lr];
            float bgb1 = vbg[n * 256 + 128 + w * 32 + 16 + lr];
#pragma unroll
            for (int mf = 0; mf < 4; ++mf)
#pragma unroll
                for (int r = 0; r < 4; ++r) {
                    float a0 = c4[mf][0][r] + bga0;
                    float b0 = c4[mf][2][r] + bgb0;
                    float x0 = a0 * sigm_f(b0) + c2[mf][0][r];
                    float a1 = c4[mf][1][r] + bga1;
                    float b1 = c4[mf][3][r] + bgb1;
                    float x1 = a1 * sigm_f(b1) + c2[mf][1][r];
                    vv[mf][0][r] = x0; vv[mf][1][r] = x1;
                    s_[mf][r] = x0 + x1;
                    q_[mf][r] = x0 * x0 + x1 * x1;
                }
            // in-wave butterfly over lr (16 lanes) -> wave-partial per row
#pragma unroll
            for (int mf = 0; mf < 4; ++mf)
#pragma unroll
                for (int r = 0; r < 4; ++r) {
#pragma unroll
                    for (int m = 1; m < 16; m <<= 1) {
                        s_[mf][r] += __shfl_xor(s_[mf][r], m);
                        q_[mf][r] += __shfl_xor(q_[mf][r], m);
                    }
                }
            if (lr == 0) {
#pragma unroll
                for (int mf = 0; mf < 4; ++mf)
#pragma unroll
                    for (int r = 0; r < 4; ++r) {
                        int row = mf * 16 + lk * 4 + r;
                        LNp[row * 8 + w * 2] = s_[mf][r];
                        LNp[row * 8 + w * 2 + 1] = q_[mf][r];
                    }
            }
        }
        __syncthreads();

        // ---- cross-wave LN finish: 4 threads per row ----
        {
            int row = tid >> 2, p = tid & 3;
            float ss = LNp[row * 8 + p * 2];
            float qq = LNp[row * 8 + p * 2 + 1];
            ss += __shfl_xor(ss, 1); qq += __shfl_xor(qq, 1);
            ss += __shfl_xor(ss, 2); qq += __shfl_xor(qq, 2);
            if (p == 0) {
                float mean = ss * (1.f / 128.f);
                float var = qq * (1.f / 128.f) - mean * mean;
                LNm[row * 2] = mean;
                LNm[row * 2 + 1] = rsqrtf(var + LN_EPS);
            }
        }
        __syncthreads();

        // ---- combine: normalize, gamma/beta, *weight, accumulate in regs ----
        {
            float ga0 = gam[n * HDIM + w * 32 + lr];
            float ga1 = gam[n * HDIM + w * 32 + 16 + lr];
            float be0 = bet[n * HDIM + w * 32 + lr];
            float be1 = bet[n * HDIM + w * 32 + 16 + lr];
#pragma unroll
            for (int mf = 0; mf < 4; ++mf)
#pragma unroll
                for (int r = 0; r < 4; ++r) {
                    int row = mf * 16 + lk * 4 + r;
                    float mean = LNm[row * 2], inv = LNm[row * 2 + 1];
                    float wgt = wsel[(size_t)(tok0 + row) * NVAR + n];
                    accO[mf][0][r] += wgt * ((vv[mf][0][r] - mean) * inv * ga0 + be0);
                    accO[mf][1][r] += wgt * ((vv[mf][1][r] - mean) * inv * ga1 + be1);
                }
        }
        // next stage writes EB; hazards separated by the barriers above.
    }

    // ---- one atomic per element per n-group ----
    {
#pragma unroll
        for (int mf = 0; mf < 4; ++mf)
#pragma unroll
            for (int r = 0; r < 4; ++r) {
                int row = mf * 16 + lk * 4 + r;
                float* po = outp + (size_t)(tok0 + row) * HDIM + w * 32 + lr;
                atomicAdd(po, accO[mf][0][r]);
                atomicAdd(po + 16, accO[mf][1][r]);
            }
    }
}

extern "C" void kernel_launch(void* const* d_in, const int* in_sizes, int n_in,
                              void* d_out, int out_size, void* d_ws, size_t ws_size,
                              hipStream_t stream) {
    const float* emb  = (const float*)d_in[0];
    const float* ctx  = (const float*)d_in[1];
    const float* fWsk = (const float*)d_in[2];
    const float* fbsk = (const float*)d_in[3];
    const float* fW1  = (const float*)d_in[4];
    const float* fb1  = (const float*)d_in[5];
    const float* fWc  = (const float*)d_in[6];
    const float* fW2  = (const float*)d_in[7];
    const float* fb2  = (const float*)d_in[8];
    const float* fWg  = (const float*)d_in[9];
    const float* fbg  = (const float*)d_in[10];
    const float* fg   = (const float*)d_in[11];
    const float* fb   = (const float*)d_in[12];
    const float* vWsk = (const float*)d_in[13];
    const float* vbsk = (const float*)d_in[14];
    const float* vW1  = (const float*)d_in[15];
    const float* vb1  = (const float*)d_in[16];
    const float* vW2  = (const float*)d_in[17];
    const float* vb2  = (const float*)d_in[18];
    const float* vWg  = (const float*)d_in[19];
    const float* vbg  = (const float*)d_in[20];
    const float* vgam = (const float*)d_in[21];
    const float* vbet = (const float*)d_in[22];

    float* outp = (float*)d_out;                       // [8192][128]
    float* wout = outp + (size_t)TOK * HDIM;           // [8192][32]

    // ---- workspace layout ----
    float* ctxp = (float*)d_ws;                        // [64][128]
    float* skip = ctxp + 64 * HDIM;                    // [8192][32] f32
    unsigned short* h1b  = (unsigned short*)(skip + (size_t)TOK * NVAR);  // [8192][128] bf16
    unsigned short* pk1  = h1b + (size_t)TOK * HDIM;   // [32][64][128]
    unsigned short* pksk = pk1 + 262144;               // [32][64][128]
    unsigned short* pk2  = pksk + 262144;              // [32][128][128]
    unsigned short* pkg  = pk2 + 524288;               // [32][128][256]
    unsigned short* pfW1 = pkg + 1048576;              // [2048][128] frag-packed
    unsigned short* pfWsk= pfW1 + 262144;              // [2048][32]
    unsigned short* pfW2 = pfWsk + 65536;              // [128][128]
    unsigned short* pfWg = pfW2 + 16384;               // [128][64]

    hipMemsetAsync(d_out, 0, (size_t)TOK * HDIM * sizeof(float), stream);
    // per-variable weight packs
    k_pack<<<dim3(16, 32), 64, 0, stream>>>(vW1, pk1, DDIM, HDIM);
    k_pack<<<dim3(16, 32), 64, 0, stream>>>(vWsk, pksk, DDIM, HDIM);
    k_pack<<<dim3(32, 32), 64, 0, stream>>>(vW2, pk2, HDIM, HDIM);
    k_pack<<<dim3(64, 32), 64, 0, stream>>>(vWg, pkg, HDIM, 2 * HDIM);
    // flatten weight packs
    k_pack<<<dim3(512, 1), 64, 0, stream>>>(fW1, pfW1, ND, HDIM);
    k_pack<<<dim3(128, 1), 64, 0, stream>>>(fWsk, pfWsk, ND, NVAR);
    k_pack<<<dim3(32, 1), 64, 0, stream>>>(fW2, pfW2, HDIM, HDIM);
    k_pack<<<dim3(16, 1), 64, 0, stream>>>(fWg, pfWg, HDIM, 64);

    k_ctx<<<64, 128, 0, stream>>>(ctx, fWc, ctxp);
    k_flat<<<256, 128, 0, stream>>>(emb, pfW1, pfWsk, fb1, fbsk, ctxp, h1b, skip);
    k_sel<<<256, 128, 0, stream>>>(h1b, skip, pfW2, fb2, pfWg, fbg, fg, fb, wout);
    k_var<<<dim3(TOK / TT, 4), 256, 0, stream>>>(emb, pk1, pksk, pk2, pkg,
                                                 vb1, vbsk, vb2, vbg, vgam, vbet,
                                                 wout, outp);
}